// Round 4
// baseline (2604.598 us; speedup 1.0000x reference)
//
#include <hip/hip_runtime.h>
#include <math.h>

#define BATCH 4096
#define TT 48
#define DDIM 59
#define HHID 256
#define RR 32              // batch rows per workgroup (2 M-tiles)
#define NWG (BATCH/RR)     // 128 workgroups
#define NTHR 512           // 8 waves

typedef _Float16 f16;
typedef _Float16 f16x8 __attribute__((ext_vector_type(8)));
typedef float    f32x4 __attribute__((ext_vector_type(4)));

// ---- output layout (floats) ----
static constexpr size_t N_XIMP   = (size_t)BATCH*TT*DDIM;
static constexpr size_t OFF_LOSS = N_XIMP;
static constexpr size_t OFF_HS   = OFF_LOSS + 1;
static constexpr size_t N_HS     = (size_t)BATCH*TT*HHID;
static constexpr size_t OFF_YOUT = OFF_HS + N_HS;
static constexpr size_t OFF_YSC  = OFF_YOUT + BATCH;
static constexpr size_t OFF_DEC  = OFF_YSC + BATCH;

// ---- f16 weight workspace layout (element offsets from wbase) ----
static constexpr size_t WOFF_GRU  = 0;          // 16 jb * 36 blocks
static constexpr size_t WOFF_DH   = 294912;     // 16 nt * 2 kt
static constexpr size_t WOFF_HIST = 311296;     // 4 nt * 8 kt
static constexpr size_t WOFF_FEAT = 327680;     // 4 nt * 2 kt
static constexpr size_t WOFF_WC   = 331776;     // 4 nt * 4 kt

__device__ __forceinline__ float sigm(float v){ return 1.f/(1.f+expf(-v)); }

// =====================================================================
// decay_factor (fully parallel; plain loads/stores — nt hurt, reverted)
// =====================================================================
__global__ __launch_bounds__(256) void decay_kernel(
    const float* __restrict__ deltas, const float* __restrict__ medians,
    const float* __restrict__ wobs_W, const float* __restrict__ wobs_b,
    float* __restrict__ out_decay)
{
  __shared__ float sW[DDIM][60];
  __shared__ float sb[64], smed[64];
  __shared__ float sdd[16][60];
  const int tid = threadIdx.x;
  for (int idx = tid; idx < DDIM*DDIM; idx += 256){
    int e = idx/DDIM, d = idx - e*DDIM;
    sW[e][d] = wobs_W[idx];
  }
  if (tid < DDIM){ sb[tid] = wobs_b[tid]; smed[tid] = medians[tid]; }
  __syncthreads();
  const size_t row0 = (size_t)blockIdx.x * 16;
  for (int idx = tid; idx < 16*DDIM; idx += 256){
    int r = idx/DDIM, d = idx - r*DDIM;
    sdd[r][d] = deltas[(row0+r)*DDIM + d] - smed[d];
  }
  __syncthreads();
  for (int idx = tid; idx < 16*DDIM; idx += 256){
    int r = idx/DDIM, e = idx - r*DDIM;
    float acc = sb[e];
    for (int d = 0; d < DDIM; d++) acc += sdd[r][d]*sW[e][d];
    float dd = sdd[r][e];
    float sg = (dd > 0.f) ? 1.f : ((dd < 0.f) ? -1.f : 0.f);
    out_decay[(row0+r)*DDIM + e] = 0.5f*(1.f - tanhf(sg*fabsf(acc)));
  }
}

// =====================================================================
// Weight conversion: fp32 -> f16 MFMA B-fragment blocks (unchanged)
// =====================================================================
__global__ __launch_bounds__(256) void conv_kernel(
    const float* __restrict__ W_dh, const float* __restrict__ hist_W,
    const float* __restrict__ feat_W, const float* __restrict__ wcomb_W,
    const float* __restrict__ W_ih, const float* __restrict__ W_hh,
    f16* __restrict__ ws)
{
  const int g  = blockIdx.x*4 + (threadIdx.x >> 6);
  const int l  = threadIdx.x & 63;
  const int nl = l & 15;
  const int kh = (l >> 4) * 8;
  f16x8 out;
  if (g < 576){                                   // GRU
    int jb = g/36, s = g - jb*36;
    if (s < 24){                                  // r or z (fused ih+hh)
      int gate = s/12, kt = s - gate*12;
      int row  = gate*256 + jb*16 + nl;
      #pragma unroll
      for (int e = 0; e < 8; e++){
        int k = kt*32 + kh + e;
        float v = (k < 256) ? W_hh[(size_t)row*256 + k]
                : (k < 374) ? W_ih[(size_t)row*118 + (k-256)] : 0.f;
        out[e] = (f16)v;
      }
    } else if (s < 32){                           // n-gate hidden part
      int kt = s - 24, row = 512 + jb*16 + nl;
      #pragma unroll
      for (int e = 0; e < 8; e++){
        int k = kt*32 + kh + e;
        out[e] = (f16)W_hh[(size_t)row*256 + k];
      }
    } else {                                      // n-gate input part
      int kt = s - 32, row = 512 + jb*16 + nl;
      #pragma unroll
      for (int e = 0; e < 8; e++){
        int k = kt*32 + kh + e;
        out[e] = (f16)((k < 118) ? W_ih[(size_t)row*118 + k] : 0.f);
      }
    }
    *(f16x8*)&ws[WOFF_GRU + (size_t)g*512 + l*8] = out;
  } else if (g < 608){                            // gamma_h decay W_dh
    int i = g - 576, nt = i >> 1, kt = i & 1;
    int row = nt*16 + nl;
    #pragma unroll
    for (int e = 0; e < 8; e++){
      int k = kt*32 + kh + e;
      out[e] = (f16)((k < 59) ? W_dh[(size_t)row*59 + k] : 0.f);
    }
    *(f16x8*)&ws[WOFF_DH + (size_t)i*512 + l*8] = out;
  } else if (g < 640){                            // hist_W
    int i = g - 608, nt = i >> 3, kt = i & 7;
    int n = nt*16 + nl;
    #pragma unroll
    for (int e = 0; e < 8; e++){
      int k = kt*32 + kh + e;
      out[e] = (f16)((n < 59) ? hist_W[(size_t)n*256 + k] : 0.f);
    }
    *(f16x8*)&ws[WOFF_HIST + (size_t)i*512 + l*8] = out;
  } else if (g < 648){                            // feat_W (off-diag mask baked in)
    int i = g - 640, nt = i >> 1, kt = i & 1;
    int n = nt*16 + nl;
    #pragma unroll
    for (int e = 0; e < 8; e++){
      int k = kt*32 + kh + e;
      out[e] = (f16)((n < 59 && k < 59 && k != n) ? feat_W[(size_t)n*59 + k] : 0.f);
    }
    *(f16x8*)&ws[WOFF_FEAT + (size_t)i*512 + l*8] = out;
  } else {                                        // wcomb_W
    int i = g - 648, nt = i >> 2, kt = i & 3;
    int n = nt*16 + nl;
    #pragma unroll
    for (int e = 0; e < 8; e++){
      int k = kt*32 + kh + e;
      out[e] = (f16)((n < 59 && k < 118) ? wcomb_W[(size_t)n*118 + k] : 0.f);
    }
    *(f16x8*)&ws[WOFF_WC + (size_t)i*512 + l*8] = out;
  }
}

// =====================================================================
// Sequential scan, RR=32: two 16-row M-tiles share every B-fragment
// load (weight traffic halved vs RR=16). Hidden state lives in
// REGISTERS (16 f32/thread); A-tiles f16 in LDS.
//   A-frag: lane l holds A[m = mt*16 + (l&15)][k = kt*32+(l>>4)*8+e]
//   C/D   : lane l, reg q -> row m = mt*16+(l>>4)*4+q, col n = nt*16+(l&15)
//   h-reg : hreg[mt][ii][q] = h[mt*16+(l>>4)*4+q][(2w+ii)*16+(l&15)]
//           (same map in gamma_h (ii) and GRU (jj) phases)
// =====================================================================
__global__ __launch_bounds__(NTHR, 1) void seq_kernel(
    const float* __restrict__ x, const float* __restrict__ mask,
    const float* __restrict__ deltas, const float* __restrict__ h0,
    const float* __restrict__ b_dh, const float* __restrict__ W_dx,
    const float* __restrict__ b_dx, const float* __restrict__ hist_b,
    const float* __restrict__ feat_b, const float* __restrict__ wcomb_b,
    const float* __restrict__ b_ih, const float* __restrict__ b_hh,
    const f16* __restrict__ wb,
    float* __restrict__ out_ximp, float* __restrict__ out_hs,
    float* __restrict__ ws_num, float* __restrict__ ws_den)
{
  __shared__ f16 Acat[RR*392];    // [h(0:256) | x_imp(256:315) | m(315:374) | pad(374:392)]
  __shared__ f16 AdAxr[RR*72];    // deltas (phases 0-2) then x_r (phases 3-4); pad 59:72
  __shared__ f16 Agm [RR*136];    // [gamma_x(0:59) | m(59:118) | pad(118:136)]
  __shared__ f16 ssx [RR*60];     // x
  __shared__ f16 sxh [RR*60];     // x_h
  __shared__ f16 sxu [RR*60];     // feat-regression output
  __shared__ f16 sbt [RR*60];     // beta
  __shared__ float sdiag[64], sbdx[64];
  __shared__ float sredN[8], sredD[8];

  const int tid = threadIdx.x;
  const int w   = tid >> 6;
  const int l   = tid & 63;
  const int nl  = l & 15;
  const int kh  = (l >> 4) * 8;
  const int mq  = (l >> 4) * 4;
  const int row0 = blockIdx.x * RR;

  const f16* Bgru  = wb + WOFF_GRU;
  const f16* Bdh   = wb + WOFF_DH;
  const f16* Bhist = wb + WOFF_HIST;
  const f16* Bfeat = wb + WOFF_FEAT;
  const f16* Bwc   = wb + WOFF_WC;

  // staging slots: 4 strided slots cover RR*59 = 1888 elements
  const int i0 = tid,          r0s = i0/59, d0s = i0 - r0s*59;
  const int i1 = tid + 512,    r1s = i1/59, d1s = i1 - r1s*59;
  const int i2 = tid + 1024,   r2s = i2/59, d2s = i2 - r2s*59;
  const int i3 = tid + 1536,   r3s = i3/59, d3s = i3 - r3s*59;
  const bool has3 = (i3 < RR*59);

  // hoisted per-thread loop-invariant biases
  const int nA = w*16 + nl;                  // waves 0-3 MFMA col (x_h / feat)
  const int nB = (w-4)*16 + nl;              // waves 4-7 MFMA col (beta)
  const float hb_n = (w < 4 && nA < DDIM) ? hist_b[nA] : 0.f;
  const float fb_n = (w < 4 && nA < DDIM) ? feat_b[nA] : 0.f;
  const float cb_n = (w >= 4 && nB < DDIM) ? wcomb_b[nB] : 0.f;
  float bdh_i[2], br_j[2], bz_j[2], bni_j[2], bnh_j[2];
  #pragma unroll
  for (int ii = 0; ii < 2; ii++){
    int n = (2*w+ii)*16 + nl;
    bdh_i[ii] = b_dh[n];
    br_j[ii]  = b_ih[n]     + b_hh[n];
    bz_j[ii]  = b_ih[256+n] + b_hh[256+n];
    bni_j[ii] = b_ih[512+n];
    bnh_j[ii] = b_hh[512+n];
  }

  if (tid < DDIM){ sdiag[tid] = W_dx[(size_t)tid*DDIM + tid]; sbdx[tid] = b_dx[tid]; }
  // zero pads (read by MFMA; matching B rows are zero, avoid garbage NaN)
  for (int idx = tid; idx < RR*18; idx += NTHR){
    int r = idx/18, c = idx - (idx/18)*18;
    Acat[r*392 + 374 + c] = (f16)0.f;
    Agm [r*136 + 118 + c] = (f16)0.f;
  }
  for (int idx = tid; idx < RR*13; idx += NTHR){
    int r = idx/13, c = idx - (idx/13)*13;
    AdAxr[r*72 + 59 + c] = (f16)0.f;
  }

  // hidden state -> registers
  float hreg[2][2][4];
  #pragma unroll
  for (int mt = 0; mt < 2; mt++)
    #pragma unroll
    for (int ii = 0; ii < 2; ii++){
      int n = (2*w+ii)*16 + nl;
      #pragma unroll
      for (int q = 0; q < 4; q++)
        hreg[mt][ii][q] = h0[(size_t)(row0 + mt*16 + mq + q)*HHID + n];
    }

  // prologue prefetch (t = 0)
  float vx0,vm0,vd0, vx1,vm1,vd1, vx2,vm2,vd2, vx3=0.f,vm3=0.f,vd3=0.f;
  {
    size_t g0 = ((size_t)(row0+r0s)*TT)*DDIM + d0s;
    size_t g1 = ((size_t)(row0+r1s)*TT)*DDIM + d1s;
    size_t g2 = ((size_t)(row0+r2s)*TT)*DDIM + d2s;
    vx0 = x[g0]; vm0 = mask[g0]; vd0 = deltas[g0];
    vx1 = x[g1]; vm1 = mask[g1]; vd1 = deltas[g1];
    vx2 = x[g2]; vm2 = mask[g2]; vd2 = deltas[g2];
    if (has3){
      size_t g3 = ((size_t)(row0+r3s)*TT)*DDIM + d3s;
      vx3 = x[g3]; vm3 = mask[g3]; vd3 = deltas[g3];
    }
  }
  __syncthreads();

  for (int t = 0; t < TT; t++){
    // ---- P0: stage prefetched x, m, d into LDS ----
    ssx[r0s*60+d0s] = (f16)vx0; AdAxr[r0s*72+d0s] = (f16)vd0;
    Agm[r0s*136+59+d0s] = (f16)vm0; Acat[r0s*392+315+d0s] = (f16)vm0;
    ssx[r1s*60+d1s] = (f16)vx1; AdAxr[r1s*72+d1s] = (f16)vd1;
    Agm[r1s*136+59+d1s] = (f16)vm1; Acat[r1s*392+315+d1s] = (f16)vm1;
    ssx[r2s*60+d2s] = (f16)vx2; AdAxr[r2s*72+d2s] = (f16)vd2;
    Agm[r2s*136+59+d2s] = (f16)vm2; Acat[r2s*392+315+d2s] = (f16)vm2;
    if (has3){
      ssx[r3s*60+d3s] = (f16)vx3; AdAxr[r3s*72+d3s] = (f16)vd3;
      Agm[r3s*136+59+d3s] = (f16)vm3; Acat[r3s*392+315+d3s] = (f16)vm3;
    }
    __syncthreads();

    // issue next step's loads (latency hidden under this step's compute)
    if (t + 1 < TT){
      size_t g0 = ((size_t)(row0+r0s)*TT + (t+1))*DDIM + d0s;
      size_t g1 = ((size_t)(row0+r1s)*TT + (t+1))*DDIM + d1s;
      size_t g2 = ((size_t)(row0+r2s)*TT + (t+1))*DDIM + d2s;
      vx0 = x[g0]; vm0 = mask[g0]; vd0 = deltas[g0];
      vx1 = x[g1]; vm1 = mask[g1]; vd1 = deltas[g1];
      vx2 = x[g2]; vm2 = mask[g2]; vd2 = deltas[g2];
      if (has3){
        size_t g3 = ((size_t)(row0+r3s)*TT + (t+1))*DDIM + d3s;
        vx3 = x[g3]; vm3 = mask[g3]; vd3 = deltas[g3];
      }
    }

    // ---- P1: gamma_h MFMA, h *= exp(-relu(.)) ; B shared across mt ----
    #pragma unroll
    for (int ii = 0; ii < 2; ii++){
      int nt = 2*w + ii;
      f32x4 acc0 = {0.f,0.f,0.f,0.f}, acc1 = {0.f,0.f,0.f,0.f};
      #pragma unroll
      for (int kt = 0; kt < 2; kt++){
        f16x8 b  = *(const f16x8*)&Bdh[(size_t)(nt*2+kt)*512 + l*8];
        f16x8 a0 = *(const f16x8*)&AdAxr[nl*72 + kt*32 + kh];
        f16x8 a1 = *(const f16x8*)&AdAxr[(16+nl)*72 + kt*32 + kh];
        acc0 = __builtin_amdgcn_mfma_f32_16x16x32_f16(a0, b, acc0, 0, 0, 0);
        acc1 = __builtin_amdgcn_mfma_f32_16x16x32_f16(a1, b, acc1, 0, 0, 0);
      }
      int n = nt*16 + nl;
      #pragma unroll
      for (int q = 0; q < 4; q++){
        float g0f = expf(-fmaxf(acc0[q] + bdh_i[ii], 0.f));
        float g1f = expf(-fmaxf(acc1[q] + bdh_i[ii], 0.f));
        float h0v = hreg[0][ii][q] * g0f;
        float h1v = hreg[1][ii][q] * g1f;
        hreg[0][ii][q] = h0v;
        hreg[1][ii][q] = h1v;
        Acat[(mq+q)*392 + n]      = (f16)h0v;
        Acat[(16+mq+q)*392 + n]   = (f16)h1v;
      }
    }
    __syncthreads();

    // ---- P2: x_h MFMA (waves 0-3) || gamma_x VALU (waves 4-7) ----
    if (w < 4){
      f32x4 acc0 = {0.f,0.f,0.f,0.f}, acc1 = {0.f,0.f,0.f,0.f};
      #pragma unroll
      for (int kt = 0; kt < 8; kt++){
        f16x8 b  = *(const f16x8*)&Bhist[(size_t)(w*8+kt)*512 + l*8];
        f16x8 a0 = *(const f16x8*)&Acat[nl*392 + kt*32 + kh];
        f16x8 a1 = *(const f16x8*)&Acat[(16+nl)*392 + kt*32 + kh];
        acc0 = __builtin_amdgcn_mfma_f32_16x16x32_f16(a0, b, acc0, 0, 0, 0);
        acc1 = __builtin_amdgcn_mfma_f32_16x16x32_f16(a1, b, acc1, 0, 0, 0);
      }
      if (nA < DDIM){
        #pragma unroll
        for (int q = 0; q < 4; q++){
          sxh[(mq+q)*60 + nA]    = (f16)(acc0[q] + hb_n);
          sxh[(16+mq+q)*60 + nA] = (f16)(acc1[q] + hb_n);
        }
      }
    } else {
      for (int idx = tid - 256; idx < RR*59; idx += 256){
        int r = idx/59, d = idx - r*59;
        float dv = (float)AdAxr[r*72 + d];
        float gx = expf(-fmaxf(dv*sdiag[d] + sbdx[d], 0.f));
        Agm[r*136 + d] = (f16)gx;
      }
    }
    __syncthreads();

    // ---- P3: x_r (overwrites AdAxr; deltas no longer needed) ----
    for (int idx = tid; idx < RR*59; idx += NTHR){
      int r = idx/59, d = idx - r*59;
      float m  = (float)Acat[r*392 + 315 + d];
      float xr = m*(float)ssx[r*60+d] + (1.f-m)*(float)sxh[r*60+d];
      AdAxr[r*72+d] = (f16)xr;
    }
    __syncthreads();

    // ---- P4: feat MFMA (waves 0-3) || beta MFMA (waves 4-7) ----
    if (w < 4){
      f32x4 acc0 = {0.f,0.f,0.f,0.f}, acc1 = {0.f,0.f,0.f,0.f};
      #pragma unroll
      for (int kt = 0; kt < 2; kt++){
        f16x8 b  = *(const f16x8*)&Bfeat[(size_t)(w*2+kt)*512 + l*8];
        f16x8 a0 = *(const f16x8*)&AdAxr[nl*72 + kt*32 + kh];
        f16x8 a1 = *(const f16x8*)&AdAxr[(16+nl)*72 + kt*32 + kh];
        acc0 = __builtin_amdgcn_mfma_f32_16x16x32_f16(a0, b, acc0, 0, 0, 0);
        acc1 = __builtin_amdgcn_mfma_f32_16x16x32_f16(a1, b, acc1, 0, 0, 0);
      }
      if (nA < DDIM){
        #pragma unroll
        for (int q = 0; q < 4; q++){
          sxu[(mq+q)*60 + nA]    = (f16)(acc0[q] + fb_n);
          sxu[(16+mq+q)*60 + nA] = (f16)(acc1[q] + fb_n);
        }
      }
    } else {
      f32x4 acc0 = {0.f,0.f,0.f,0.f}, acc1 = {0.f,0.f,0.f,0.f};
      #pragma unroll
      for (int kt = 0; kt < 4; kt++){
        f16x8 b  = *(const f16x8*)&Bwc[(size_t)((w-4)*4+kt)*512 + l*8];
        f16x8 a0 = *(const f16x8*)&Agm[nl*136 + kt*32 + kh];
        f16x8 a1 = *(const f16x8*)&Agm[(16+nl)*136 + kt*32 + kh];
        acc0 = __builtin_amdgcn_mfma_f32_16x16x32_f16(a0, b, acc0, 0, 0, 0);
        acc1 = __builtin_amdgcn_mfma_f32_16x16x32_f16(a1, b, acc1, 0, 0, 0);
      }
      if (nB < DDIM){
        #pragma unroll
        for (int q = 0; q < 4; q++){
          sbt[(mq+q)*60 + nB]    = (f16)sigm(acc0[q] + cb_n);
          sbt[(16+mq+q)*60 + nB] = (f16)sigm(acc1[q] + cb_n);
        }
      }
    }
    __syncthreads();

    // ---- P5: x_comb / loss / x_imp ----
    float lnum = 0.f, lden = 0.f;
    for (int idx = tid; idx < RR*59; idx += NTHR){
      int r = idx/59, i = idx - r*59;
      float xh = (float)sxh[r*60+i], xu = (float)sxu[r*60+i], bt = (float)sbt[r*60+i];
      float xc = bt*xu + (1.f-bt)*xh;
      float m = (float)Acat[r*392 + 315 + i];
      float xv = (float)ssx[r*60+i];
      lnum += fabsf(xv - xc)*m;
      lden += m;
      float xi = m*xv + (1.f-m)*xc;
      Acat[r*392 + 256 + i] = (f16)xi;
      out_ximp[((size_t)(row0+r)*TT + t)*DDIM + i] = xi;
    }
    #pragma unroll
    for (int off = 32; off >= 1; off >>= 1){
      lnum += __shfl_xor(lnum, off);
      lden += __shfl_xor(lden, off);
    }
    if (l == 0){ sredN[w] = lnum; sredD[w] = lden; }
    __syncthreads();
    if (tid == 0){
      float a = 0.f, b = 0.f;
      #pragma unroll
      for (int k = 0; k < 8; k++){ a += sredN[k]; b += sredD[k]; }
      atomicAdd(&ws_num[t], a); atomicAdd(&ws_den[t], b);
    }

    // ---- P6: GRU MFMA; every B-frag feeds both M-tiles ----
    #pragma unroll
    for (int jj = 0; jj < 2; jj++){
      int jb = 2*w + jj;
      const f16* Bb = Bgru + (size_t)jb*36*512;
      f32x4 ar0={0,0,0,0}, az0={0,0,0,0}, anh0={0,0,0,0}, ani0={0,0,0,0};
      f32x4 ar1={0,0,0,0}, az1={0,0,0,0}, anh1={0,0,0,0}, ani1={0,0,0,0};
      #pragma unroll
      for (int kt = 0; kt < 12; kt++){
        f16x8 a0 = *(const f16x8*)&Acat[nl*392 + kt*32 + kh];
        f16x8 a1 = *(const f16x8*)&Acat[(16+nl)*392 + kt*32 + kh];
        f16x8 br = *(const f16x8*)&Bb[(size_t)kt*512 + l*8];
        f16x8 bz = *(const f16x8*)&Bb[(size_t)(12+kt)*512 + l*8];
        ar0 = __builtin_amdgcn_mfma_f32_16x16x32_f16(a0, br, ar0, 0, 0, 0);
        ar1 = __builtin_amdgcn_mfma_f32_16x16x32_f16(a1, br, ar1, 0, 0, 0);
        az0 = __builtin_amdgcn_mfma_f32_16x16x32_f16(a0, bz, az0, 0, 0, 0);
        az1 = __builtin_amdgcn_mfma_f32_16x16x32_f16(a1, bz, az1, 0, 0, 0);
        if (kt < 8){
          f16x8 bn = *(const f16x8*)&Bb[(size_t)(24+kt)*512 + l*8];
          anh0 = __builtin_amdgcn_mfma_f32_16x16x32_f16(a0, bn, anh0, 0, 0, 0);
          anh1 = __builtin_amdgcn_mfma_f32_16x16x32_f16(a1, bn, anh1, 0, 0, 0);
        } else {
          f16x8 bn = *(const f16x8*)&Bb[(size_t)(32+kt-8)*512 + l*8];
          ani0 = __builtin_amdgcn_mfma_f32_16x16x32_f16(a0, bn, ani0, 0, 0, 0);
          ani1 = __builtin_amdgcn_mfma_f32_16x16x32_f16(a1, bn, ani1, 0, 0, 0);
        }
      }
      int j = jb*16 + nl;
      #pragma unroll
      for (int q = 0; q < 4; q++){
        float rg = sigm(ar0[q] + br_j[jj]);
        float zg = sigm(az0[q] + bz_j[jj]);
        float ng = tanhf(ani0[q] + bni_j[jj] + rg*(anh0[q] + bnh_j[jj]));
        float hn = (1.f-zg)*ng + zg*hreg[0][jj][q];
        hreg[0][jj][q] = hn;
        out_hs[((size_t)(row0+mq+q)*TT + t)*HHID + j] = hn;

        rg = sigm(ar1[q] + br_j[jj]);
        zg = sigm(az1[q] + bz_j[jj]);
        ng = tanhf(ani1[q] + bni_j[jj] + rg*(anh1[q] + bnh_j[jj]));
        hn = (1.f-zg)*ng + zg*hreg[1][jj][q];
        hreg[1][jj][q] = hn;
        out_hs[((size_t)(row0+16+mq+q)*TT + t)*HHID + j] = hn;
      }
    }
    __syncthreads();
  }
}

// =====================================================================
// finalize: x_loss and classification head
// =====================================================================
__global__ __launch_bounds__(256) void final_kernel(
    const float* __restrict__ hs, const float* __restrict__ cls_W,
    const float* __restrict__ cls_b, const float* __restrict__ ws_num,
    const float* __restrict__ ws_den, float* __restrict__ out)
{
  int b = blockIdx.x*256 + threadIdx.x;
  if (b < BATCH){
    const float* hr = hs + ((size_t)b*TT + (TT-1))*HHID;
    float acc = cls_b[0];
    for (int j = 0; j < HHID; j++) acc += hr[j]*cls_W[j];
    out[OFF_YOUT + b] = acc;
    out[OFF_YSC  + b] = sigm(acc);
  }
  if (blockIdx.x == 0 && threadIdx.x == 0){
    float s = 0.f;
    for (int tt = 0; tt < TT; tt++) s += ws_num[tt]/(ws_den[tt] + 1e-5f);
    out[OFF_LOSS] = s;
  }
}

extern "C" void kernel_launch(void* const* d_in, const int* in_sizes, int n_in,
                              void* d_out, int out_size, void* d_ws, size_t ws_size,
                              hipStream_t stream)
{
  const float* x       = (const float*)d_in[0];
  const float* mask_   = (const float*)d_in[1];
  const float* deltas  = (const float*)d_in[2];
  const float* h0      = (const float*)d_in[4];
  const float* medians = (const float*)d_in[5];
  const float* W_dh    = (const float*)d_in[6];
  const float* b_dh    = (const float*)d_in[7];
  const float* W_dx    = (const float*)d_in[8];
  const float* b_dx    = (const float*)d_in[9];
  const float* hist_W  = (const float*)d_in[10];
  const float* hist_b  = (const float*)d_in[11];
  const float* feat_W  = (const float*)d_in[12];
  const float* feat_b  = (const float*)d_in[13];
  const float* wcomb_W = (const float*)d_in[14];
  const float* wcomb_b = (const float*)d_in[15];
  const float* wobs_W  = (const float*)d_in[16];
  const float* wobs_b  = (const float*)d_in[17];
  const float* W_ih    = (const float*)d_in[18];
  const float* W_hh    = (const float*)d_in[19];
  const float* b_ih    = (const float*)d_in[20];
  const float* b_hh    = (const float*)d_in[21];
  const float* cls_W   = (const float*)d_in[22];
  const float* cls_b   = (const float*)d_in[23];

  float* out    = (float*)d_out;
  float* ws_num = (float*)d_ws;              // 48 floats
  float* ws_den = ws_num + TT;               // 48 floats
  f16*   wbase  = (f16*)((char*)d_ws + 512); // f16 weight blocks

  hipMemsetAsync(d_ws, 0, 512, stream);

  conv_kernel<<<166, 256, 0, stream>>>(W_dh, hist_W, feat_W, wcomb_W,
                                       W_ih, W_hh, wbase);

  decay_kernel<<<BATCH*TT/16, 256, 0, stream>>>(deltas, medians, wobs_W, wobs_b,
                                                out + OFF_DEC);

  seq_kernel<<<NWG, NTHR, 0, stream>>>(x, mask_, deltas, h0,
      b_dh, W_dx, b_dx, hist_b, feat_b, wcomb_b, b_ih, b_hh, wbase,
      out /*x_imp*/, out + OFF_HS, ws_num, ws_den);

  final_kernel<<<BATCH/256, 256, 0, stream>>>(out + OFF_HS, cls_W, cls_b,
                                              ws_num, ws_den, out);
}

// Round 5
// 1726.651 us; speedup vs baseline: 1.5085x; 1.5085x over previous
//
#include <hip/hip_runtime.h>
#include <math.h>

#define BATCH 4096
#define TT 48
#define DDIM 59
#define HHID 256
#define RR 16              // batch rows per workgroup
#define NWG (BATCH/RR)     // 256 workgroups (1 per CU)
#define NTHR 1024          // 16 waves

typedef _Float16 f16;
typedef _Float16 f16x8 __attribute__((ext_vector_type(8)));
typedef float    f32x4 __attribute__((ext_vector_type(4)));

// ---- output layout (floats) ----
static constexpr size_t N_XIMP   = (size_t)BATCH*TT*DDIM;
static constexpr size_t OFF_LOSS = N_XIMP;
static constexpr size_t OFF_HS   = OFF_LOSS + 1;
static constexpr size_t N_HS     = (size_t)BATCH*TT*HHID;
static constexpr size_t OFF_YOUT = OFF_HS + N_HS;
static constexpr size_t OFF_YSC  = OFF_YOUT + BATCH;
static constexpr size_t OFF_DEC  = OFF_YSC + BATCH;

// ---- f16 weight workspace layout (element offsets from wbase) ----
static constexpr size_t WOFF_GRU  = 0;          // 16 jb * 36 blocks
static constexpr size_t WOFF_DH   = 294912;     // 16 nt * 2 kt
static constexpr size_t WOFF_HIST = 311296;     // 4 nt * 8 kt
static constexpr size_t WOFF_FEAT = 327680;     // 4 nt * 2 kt
static constexpr size_t WOFF_WC   = 331776;     // 4 nt * 4 kt

__device__ __forceinline__ float sigm(float v){ return 1.f/(1.f+expf(-v)); }

// =====================================================================
// decay_factor (fully parallel)
// =====================================================================
__global__ __launch_bounds__(256) void decay_kernel(
    const float* __restrict__ deltas, const float* __restrict__ medians,
    const float* __restrict__ wobs_W, const float* __restrict__ wobs_b,
    float* __restrict__ out_decay)
{
  __shared__ float sW[DDIM][60];
  __shared__ float sb[64], smed[64];
  __shared__ float sdd[16][60];
  const int tid = threadIdx.x;
  for (int idx = tid; idx < DDIM*DDIM; idx += 256){
    int e = idx/DDIM, d = idx - e*DDIM;
    sW[e][d] = wobs_W[idx];
  }
  if (tid < DDIM){ sb[tid] = wobs_b[tid]; smed[tid] = medians[tid]; }
  __syncthreads();
  const size_t row0 = (size_t)blockIdx.x * 16;
  for (int idx = tid; idx < 16*DDIM; idx += 256){
    int r = idx/DDIM, d = idx - r*DDIM;
    sdd[r][d] = deltas[(row0+r)*DDIM + d] - smed[d];
  }
  __syncthreads();
  for (int idx = tid; idx < 16*DDIM; idx += 256){
    int r = idx/DDIM, e = idx - r*DDIM;
    float acc = sb[e];
    for (int d = 0; d < DDIM; d++) acc += sdd[r][d]*sW[e][d];
    float dd = sdd[r][e];
    float sg = (dd > 0.f) ? 1.f : ((dd < 0.f) ? -1.f : 0.f);
    out_decay[(row0+r)*DDIM + e] = 0.5f*(1.f - tanhf(sg*fabsf(acc)));
  }
}

// =====================================================================
// Weight conversion: fp32 -> f16 MFMA B-fragment blocks (unchanged)
// =====================================================================
__global__ __launch_bounds__(256) void conv_kernel(
    const float* __restrict__ W_dh, const float* __restrict__ hist_W,
    const float* __restrict__ feat_W, const float* __restrict__ wcomb_W,
    const float* __restrict__ W_ih, const float* __restrict__ W_hh,
    f16* __restrict__ ws)
{
  const int g  = blockIdx.x*4 + (threadIdx.x >> 6);
  const int l  = threadIdx.x & 63;
  const int nl = l & 15;
  const int kh = (l >> 4) * 8;
  f16x8 out;
  if (g < 576){                                   // GRU
    int jb = g/36, s = g - jb*36;
    if (s < 24){                                  // r or z (fused ih+hh)
      int gate = s/12, kt = s - gate*12;
      int row  = gate*256 + jb*16 + nl;
      #pragma unroll
      for (int e = 0; e < 8; e++){
        int k = kt*32 + kh + e;
        float v = (k < 256) ? W_hh[(size_t)row*256 + k]
                : (k < 374) ? W_ih[(size_t)row*118 + (k-256)] : 0.f;
        out[e] = (f16)v;
      }
    } else if (s < 32){                           // n-gate hidden part
      int kt = s - 24, row = 512 + jb*16 + nl;
      #pragma unroll
      for (int e = 0; e < 8; e++){
        int k = kt*32 + kh + e;
        out[e] = (f16)W_hh[(size_t)row*256 + k];
      }
    } else {                                      // n-gate input part
      int kt = s - 32, row = 512 + jb*16 + nl;
      #pragma unroll
      for (int e = 0; e < 8; e++){
        int k = kt*32 + kh + e;
        out[e] = (f16)((k < 118) ? W_ih[(size_t)row*118 + k] : 0.f);
      }
    }
    *(f16x8*)&ws[WOFF_GRU + (size_t)g*512 + l*8] = out;
  } else if (g < 608){                            // gamma_h decay W_dh
    int i = g - 576, nt = i >> 1, kt = i & 1;
    int row = nt*16 + nl;
    #pragma unroll
    for (int e = 0; e < 8; e++){
      int k = kt*32 + kh + e;
      out[e] = (f16)((k < 59) ? W_dh[(size_t)row*59 + k] : 0.f);
    }
    *(f16x8*)&ws[WOFF_DH + (size_t)i*512 + l*8] = out;
  } else if (g < 640){                            // hist_W
    int i = g - 608, nt = i >> 3, kt = i & 7;
    int n = nt*16 + nl;
    #pragma unroll
    for (int e = 0; e < 8; e++){
      int k = kt*32 + kh + e;
      out[e] = (f16)((n < 59) ? hist_W[(size_t)n*256 + k] : 0.f);
    }
    *(f16x8*)&ws[WOFF_HIST + (size_t)i*512 + l*8] = out;
  } else if (g < 648){                            // feat_W (off-diag mask baked in)
    int i = g - 640, nt = i >> 1, kt = i & 1;
    int n = nt*16 + nl;
    #pragma unroll
    for (int e = 0; e < 8; e++){
      int k = kt*32 + kh + e;
      out[e] = (f16)((n < 59 && k < 59 && k != n) ? feat_W[(size_t)n*59 + k] : 0.f);
    }
    *(f16x8*)&ws[WOFF_FEAT + (size_t)i*512 + l*8] = out;
  } else {                                        // wcomb_W
    int i = g - 648, nt = i >> 2, kt = i & 3;
    int n = nt*16 + nl;
    #pragma unroll
    for (int e = 0; e < 8; e++){
      int k = kt*32 + kh + e;
      out[e] = (f16)((n < 59 && k < 118) ? wcomb_W[(size_t)n*118 + k] : 0.f);
    }
    *(f16x8*)&ws[WOFF_WC + (size_t)i*512 + l*8] = out;
  }
}

// =====================================================================
// Sequential scan: 16 waves/WG, RR=16, NWG=256 (1 WG/CU, 16 waves/CU).
// GRU split: h-dependent K (kt 0-7) in P2 (1 jb per wave, accumulators
// persist in VGPRs), x_imp-dependent K (kt 8-11) in P6.
// Phases: P0 stage | P1 gamma_h+gamma_x | P2 GRU-hh + x_h + beta |
//         P3 x_r | P4 feat | P5 x_comb/loss | P6 GRU finish
// =====================================================================
__global__ __launch_bounds__(NTHR) void seq_kernel(
    const float* __restrict__ x, const float* __restrict__ mask,
    const float* __restrict__ deltas, const float* __restrict__ h0,
    const float* __restrict__ b_dh, const float* __restrict__ W_dx,
    const float* __restrict__ b_dx, const float* __restrict__ hist_b,
    const float* __restrict__ feat_b, const float* __restrict__ wcomb_b,
    const float* __restrict__ b_ih, const float* __restrict__ b_hh,
    const f16* __restrict__ wb,
    float* __restrict__ out_ximp, float* __restrict__ out_hs,
    float* __restrict__ ws_num, float* __restrict__ ws_den)
{
  __shared__ f16 Acat[RR*392];    // [h(0:256) | x_imp(256:315) | m(315:374) | pad]
  __shared__ f16 AdAxr[RR*72];    // deltas (P0-P1) then x_r (P3-P4); pad 59:72
  __shared__ f16 Agm [RR*136];    // [gamma_x(0:59) | m(59:118) | pad]
  __shared__ f16 ssx [RR*60];     // x
  __shared__ f16 sxh [RR*60];     // x_h
  __shared__ f16 sxu [RR*60];     // feat output
  __shared__ f16 sbt [RR*60];     // beta
  __shared__ float sh [RR*260];   // fp32 hidden state
  __shared__ float sdiag[64], sbdx[64];
  __shared__ float sredN[16], sredD[16];

  const int tid = threadIdx.x;
  const int w   = tid >> 6;          // 0..15
  const int l   = tid & 63;
  const int nl  = l & 15;
  const int kh  = (l >> 4) * 8;
  const int mq  = (l >> 4) * 4;
  const int row0 = blockIdx.x * RR;

  const f16* Bgru  = wb + WOFF_GRU;
  const f16* Bdh   = wb + WOFF_DH;
  const f16* Bhist = wb + WOFF_HIST;
  const f16* Bfeat = wb + WOFF_FEAT;
  const f16* Bwc   = wb + WOFF_WC;
  const f16* Bb    = Bgru + (size_t)w*36*512;   // this wave's GRU jb slice

  // staging slot (single: 944 < 1024 threads)
  const bool hasS = (tid < RR*DDIM);
  const int r0s = tid/59, d0s = tid - r0s*59;

  // hoisted per-thread biases
  const int nG = w*16 + nl;                       // gamma_h col & GRU j
  const float bdh_n = b_dh[nG];
  const float br_j  = b_ih[nG]     + b_hh[nG];
  const float bz_j  = b_ih[256+nG] + b_hh[256+nG];
  const float bni_j = b_ih[512+nG];
  const float bnh_j = b_hh[512+nG];
  const int nA = w*16 + nl;                       // waves 0-3: x_h/feat col
  const int nB = (w-4)*16 + nl;                   // waves 4-7: beta col
  const float hb_n = (w < 4 && nA < DDIM) ? hist_b[nA] : 0.f;
  const float fb_n = (w < 4 && nA < DDIM) ? feat_b[nA] : 0.f;
  const float cb_n = (w >= 4 && w < 8 && nB < DDIM) ? wcomb_b[nB] : 0.f;

  if (tid < DDIM){ sdiag[tid] = W_dx[(size_t)tid*DDIM + tid]; sbdx[tid] = b_dx[tid]; }
  // zero pads once
  for (int idx = tid; idx < RR*18; idx += NTHR){
    int r = idx/18, c = idx - (idx/18)*18;
    Acat[r*392 + 374 + c] = (f16)0.f;
    Agm [r*136 + 118 + c] = (f16)0.f;
  }
  for (int idx = tid; idx < RR*13; idx += NTHR){
    int r = idx/13, c = idx - (idx/13)*13;
    AdAxr[r*72 + 59 + c] = (f16)0.f;
  }
  for (int idx = tid; idx < RR*HHID; idx += NTHR){
    int r = idx >> 8, j = idx & 255;
    sh[r*260 + j] = h0[(size_t)(row0+r)*HHID + j];
  }

  // prologue prefetch (t = 0)
  float vx0 = 0.f, vm0 = 0.f, vd0 = 0.f;
  if (hasS){
    size_t g0 = ((size_t)(row0+r0s)*TT)*DDIM + d0s;
    vx0 = x[g0]; vm0 = mask[g0]; vd0 = deltas[g0];
  }
  __syncthreads();

  for (int t = 0; t < TT; t++){
    // ---- P0: stage prefetched x, m, d ----
    if (hasS){
      ssx[r0s*60+d0s] = (f16)vx0;
      AdAxr[r0s*72+d0s] = (f16)vd0;
      Agm[r0s*136+59+d0s] = (f16)vm0;
      Acat[r0s*392+315+d0s] = (f16)vm0;
    }
    __syncthreads();

    // issue next step's loads (latency hidden under compute)
    if (t + 1 < TT && hasS){
      size_t g0 = ((size_t)(row0+r0s)*TT + (t+1))*DDIM + d0s;
      vx0 = x[g0]; vm0 = mask[g0]; vd0 = deltas[g0];
    }

    // ---- P1: gamma_h MFMA (1 nt per wave) + gamma_x VALU ----
    {
      f32x4 acc = {0.f,0.f,0.f,0.f};
      #pragma unroll
      for (int kt = 0; kt < 2; kt++){
        f16x8 a = *(const f16x8*)&AdAxr[nl*72 + kt*32 + kh];
        f16x8 b = *(const f16x8*)&Bdh[(size_t)(w*2+kt)*512 + l*8];
        acc = __builtin_amdgcn_mfma_f32_16x16x32_f16(a, b, acc, 0, 0, 0);
      }
      #pragma unroll
      for (int q = 0; q < 4; q++){
        float gm = expf(-fmaxf(acc[q] + bdh_n, 0.f));
        float hv = sh[(mq+q)*260 + nG] * gm;
        sh[(mq+q)*260 + nG] = hv;
        Acat[(mq+q)*392 + nG] = (f16)hv;
      }
      if (hasS){
        float dv = (float)AdAxr[r0s*72 + d0s];
        float gx = expf(-fmaxf(dv*sdiag[d0s] + sbdx[d0s], 0.f));
        Agm[r0s*136 + d0s] = (f16)gx;
      }
    }
    __syncthreads();

    // ---- P2: GRU h-part (all 16 waves, kt 0-7) then x_h / beta ----
    f32x4 gr = {0.f,0.f,0.f,0.f}, gz = {0.f,0.f,0.f,0.f}, gnh = {0.f,0.f,0.f,0.f};
    {
      #pragma unroll
      for (int kt = 0; kt < 8; kt++){
        f16x8 a  = *(const f16x8*)&Acat[nl*392 + kt*32 + kh];
        f16x8 br = *(const f16x8*)&Bb[(size_t)kt*512 + l*8];
        f16x8 bz = *(const f16x8*)&Bb[(size_t)(12+kt)*512 + l*8];
        f16x8 bn = *(const f16x8*)&Bb[(size_t)(24+kt)*512 + l*8];
        gr  = __builtin_amdgcn_mfma_f32_16x16x32_f16(a, br, gr, 0, 0, 0);
        gz  = __builtin_amdgcn_mfma_f32_16x16x32_f16(a, bz, gz, 0, 0, 0);
        gnh = __builtin_amdgcn_mfma_f32_16x16x32_f16(a, bn, gnh, 0, 0, 0);
      }
      if (w < 4){                               // x_h
        f32x4 acc = {0.f,0.f,0.f,0.f};
        #pragma unroll
        for (int kt = 0; kt < 8; kt++){
          f16x8 a = *(const f16x8*)&Acat[nl*392 + kt*32 + kh];
          f16x8 b = *(const f16x8*)&Bhist[(size_t)(w*8+kt)*512 + l*8];
          acc = __builtin_amdgcn_mfma_f32_16x16x32_f16(a, b, acc, 0, 0, 0);
        }
        if (nA < DDIM){
          #pragma unroll
          for (int q = 0; q < 4; q++) sxh[(mq+q)*60 + nA] = (f16)(acc[q] + hb_n);
        }
      } else if (w < 8){                        // beta
        f32x4 acc = {0.f,0.f,0.f,0.f};
        #pragma unroll
        for (int kt = 0; kt < 4; kt++){
          f16x8 a = *(const f16x8*)&Agm[nl*136 + kt*32 + kh];
          f16x8 b = *(const f16x8*)&Bwc[(size_t)((w-4)*4+kt)*512 + l*8];
          acc = __builtin_amdgcn_mfma_f32_16x16x32_f16(a, b, acc, 0, 0, 0);
        }
        if (nB < DDIM){
          #pragma unroll
          for (int q = 0; q < 4; q++) sbt[(mq+q)*60 + nB] = (f16)sigm(acc[q] + cb_n);
        }
      }
    }
    __syncthreads();

    // ---- P3: x_r (overwrites AdAxr) ----
    if (hasS){
      float m  = (float)Acat[r0s*392 + 315 + d0s];
      float xr = m*(float)ssx[r0s*60+d0s] + (1.f-m)*(float)sxh[r0s*60+d0s];
      AdAxr[r0s*72+d0s] = (f16)xr;
    }
    __syncthreads();

    // ---- P4: feat MFMA (waves 0-3) ----
    if (w < 4){
      f32x4 acc = {0.f,0.f,0.f,0.f};
      #pragma unroll
      for (int kt = 0; kt < 2; kt++){
        f16x8 a = *(const f16x8*)&AdAxr[nl*72 + kt*32 + kh];
        f16x8 b = *(const f16x8*)&Bfeat[(size_t)(w*2+kt)*512 + l*8];
        acc = __builtin_amdgcn_mfma_f32_16x16x32_f16(a, b, acc, 0, 0, 0);
      }
      if (nA < DDIM){
        #pragma unroll
        for (int q = 0; q < 4; q++) sxu[(mq+q)*60 + nA] = (f16)(acc[q] + fb_n);
      }
    }
    __syncthreads();

    // ---- P5: x_comb / loss / x_imp ----
    float lnum = 0.f, lden = 0.f;
    if (hasS){
      float xh = (float)sxh[r0s*60+d0s], xu = (float)sxu[r0s*60+d0s];
      float bt = (float)sbt[r0s*60+d0s];
      float xc = bt*xu + (1.f-bt)*xh;
      float m  = (float)Acat[r0s*392 + 315 + d0s];
      float xv = (float)ssx[r0s*60+d0s];
      lnum = fabsf(xv - xc)*m;
      lden = m;
      float xi = m*xv + (1.f-m)*xc;
      Acat[r0s*392 + 256 + d0s] = (f16)xi;
      out_ximp[((size_t)(row0+r0s)*TT + t)*DDIM + d0s] = xi;
    }
    #pragma unroll
    for (int off = 32; off >= 1; off >>= 1){
      lnum += __shfl_xor(lnum, off);
      lden += __shfl_xor(lden, off);
    }
    if (l == 0){ sredN[w] = lnum; sredD[w] = lden; }
    __syncthreads();
    if (tid == 0){
      float a = 0.f, b = 0.f;
      #pragma unroll
      for (int k = 0; k < 16; k++){ a += sredN[k]; b += sredD[k]; }
      atomicAdd(&ws_num[t], a); atomicAdd(&ws_den[t], b);
    }

    // ---- P6: GRU finish (kt 8-11 over [x_imp|m]) + gates + h update ----
    {
      f32x4 gni = {0.f,0.f,0.f,0.f};
      #pragma unroll
      for (int kt = 8; kt < 12; kt++){
        f16x8 a  = *(const f16x8*)&Acat[nl*392 + kt*32 + kh];
        f16x8 br = *(const f16x8*)&Bb[(size_t)kt*512 + l*8];
        f16x8 bz = *(const f16x8*)&Bb[(size_t)(12+kt)*512 + l*8];
        f16x8 bn = *(const f16x8*)&Bb[(size_t)(32+kt-8)*512 + l*8];
        gr  = __builtin_amdgcn_mfma_f32_16x16x32_f16(a, br, gr, 0, 0, 0);
        gz  = __builtin_amdgcn_mfma_f32_16x16x32_f16(a, bz, gz, 0, 0, 0);
        gni = __builtin_amdgcn_mfma_f32_16x16x32_f16(a, bn, gni, 0, 0, 0);
      }
      #pragma unroll
      for (int q = 0; q < 4; q++){
        float rg = sigm(gr[q] + br_j);
        float zg = sigm(gz[q] + bz_j);
        float ng = tanhf(gni[q] + bni_j + rg*(gnh[q] + bnh_j));
        float hold = sh[(mq+q)*260 + nG];
        float hn = (1.f-zg)*ng + zg*hold;
        sh[(mq+q)*260 + nG] = hn;
        out_hs[((size_t)(row0+mq+q)*TT + t)*HHID + nG] = hn;
      }
    }
    __syncthreads();
  }
}

// =====================================================================
// finalize: x_loss and classification head
// =====================================================================
__global__ __launch_bounds__(256) void final_kernel(
    const float* __restrict__ hs, const float* __restrict__ cls_W,
    const float* __restrict__ cls_b, const float* __restrict__ ws_num,
    const float* __restrict__ ws_den, float* __restrict__ out)
{
  int b = blockIdx.x*256 + threadIdx.x;
  if (b < BATCH){
    const float* hr = hs + ((size_t)b*TT + (TT-1))*HHID;
    float acc = cls_b[0];
    for (int j = 0; j < HHID; j++) acc += hr[j]*cls_W[j];
    out[OFF_YOUT + b] = acc;
    out[OFF_YSC  + b] = sigm(acc);
  }
  if (blockIdx.x == 0 && threadIdx.x == 0){
    float s = 0.f;
    for (int tt = 0; tt < TT; tt++) s += ws_num[tt]/(ws_den[tt] + 1e-5f);
    out[OFF_LOSS] = s;
  }
}

extern "C" void kernel_launch(void* const* d_in, const int* in_sizes, int n_in,
                              void* d_out, int out_size, void* d_ws, size_t ws_size,
                              hipStream_t stream)
{
  const float* x       = (const float*)d_in[0];
  const float* mask_   = (const float*)d_in[1];
  const float* deltas  = (const float*)d_in[2];
  const float* h0      = (const float*)d_in[4];
  const float* medians = (const float*)d_in[5];
  const float* W_dh    = (const float*)d_in[6];
  const float* b_dh    = (const float*)d_in[7];
  const float* W_dx    = (const float*)d_in[8];
  const float* b_dx    = (const float*)d_in[9];
  const float* hist_W  = (const float*)d_in[10];
  const float* hist_b  = (const float*)d_in[11];
  const float* feat_W  = (const float*)d_in[12];
  const float* feat_b  = (const float*)d_in[13];
  const float* wcomb_W = (const float*)d_in[14];
  const float* wcomb_b = (const float*)d_in[15];
  const float* wobs_W  = (const float*)d_in[16];
  const float* wobs_b  = (const float*)d_in[17];
  const float* W_ih    = (const float*)d_in[18];
  const float* W_hh    = (const float*)d_in[19];
  const float* b_ih    = (const float*)d_in[20];
  const float* b_hh    = (const float*)d_in[21];
  const float* cls_W   = (const float*)d_in[22];
  const float* cls_b   = (const float*)d_in[23];

  float* out    = (float*)d_out;
  float* ws_num = (float*)d_ws;              // 48 floats
  float* ws_den = ws_num + TT;               // 48 floats
  f16*   wbase  = (f16*)((char*)d_ws + 512); // f16 weight blocks

  hipMemsetAsync(d_ws, 0, 512, stream);

  conv_kernel<<<166, 256, 0, stream>>>(W_dh, hist_W, feat_W, wcomb_W,
                                       W_ih, W_hh, wbase);

  decay_kernel<<<BATCH*TT/16, 256, 0, stream>>>(deltas, medians, wobs_W, wobs_b,
                                                out + OFF_DEC);

  seq_kernel<<<NWG, NTHR, 0, stream>>>(x, mask_, deltas, h0,
      b_dh, W_dx, b_dx, hist_b, feat_b, wcomb_b, b_ih, b_hh, wbase,
      out /*x_imp*/, out + OFF_HS, ws_num, ws_den);

  final_kernel<<<BATCH/256, 256, 0, stream>>>(out + OFF_HS, cls_W, cls_b,
                                              ws_num, ws_den, out);
}

// Round 6
// 1524.176 us; speedup vs baseline: 1.7089x; 1.1328x over previous
//
#include <hip/hip_runtime.h>
#include <math.h>

#define BATCH 4096
#define TT 48
#define DDIM 59
#define HHID 256
#define RR 16              // batch rows per workgroup
#define NWG (BATCH/RR)     // 256 workgroups (1 per CU)
#define NTHR 1024          // 16 waves

typedef _Float16 f16;
typedef _Float16 f16x8 __attribute__((ext_vector_type(8)));
typedef float    f32x4 __attribute__((ext_vector_type(4)));

// ---- output layout (floats) ----
static constexpr size_t N_XIMP   = (size_t)BATCH*TT*DDIM;
static constexpr size_t OFF_LOSS = N_XIMP;
static constexpr size_t OFF_HS   = OFF_LOSS + 1;
static constexpr size_t N_HS     = (size_t)BATCH*TT*HHID;
static constexpr size_t OFF_YOUT = OFF_HS + N_HS;
static constexpr size_t OFF_YSC  = OFF_YOUT + BATCH;
static constexpr size_t OFF_DEC  = OFF_YSC + BATCH;

// ---- f16 weight workspace layout (element offsets from wbase) ----
static constexpr size_t WOFF_GRU  = 0;          // 16 jb * 36 blocks
static constexpr size_t WOFF_DH   = 294912;     // 16 nt * 2 kt
static constexpr size_t WOFF_HIST = 311296;     // 4 nt * 8 kt
static constexpr size_t WOFF_FEAT = 327680;     // 4 nt * 2 kt
static constexpr size_t WOFF_WC   = 331776;     // 4 nt * 4 kt

__device__ __forceinline__ float sigm(float v){ return 1.f/(1.f+expf(-v)); }

// =====================================================================
// decay_factor (fully parallel); nt loads on read-once deltas
// =====================================================================
__global__ __launch_bounds__(256) void decay_kernel(
    const float* __restrict__ deltas, const float* __restrict__ medians,
    const float* __restrict__ wobs_W, const float* __restrict__ wobs_b,
    float* __restrict__ out_decay)
{
  __shared__ float sW[DDIM][60];
  __shared__ float sb[64], smed[64];
  __shared__ float sdd[16][60];
  const int tid = threadIdx.x;
  for (int idx = tid; idx < DDIM*DDIM; idx += 256){
    int e = idx/DDIM, d = idx - e*DDIM;
    sW[e][d] = wobs_W[idx];
  }
  if (tid < DDIM){ sb[tid] = wobs_b[tid]; smed[tid] = medians[tid]; }
  __syncthreads();
  const size_t row0 = (size_t)blockIdx.x * 16;
  for (int idx = tid; idx < 16*DDIM; idx += 256){
    int r = idx/DDIM, d = idx - r*DDIM;
    sdd[r][d] = __builtin_nontemporal_load(&deltas[(row0+r)*DDIM + d]) - smed[d];
  }
  __syncthreads();
  for (int idx = tid; idx < 16*DDIM; idx += 256){
    int r = idx/DDIM, e = idx - r*DDIM;
    float acc = sb[e];
    for (int d = 0; d < DDIM; d++) acc += sdd[r][d]*sW[e][d];
    float dd = sdd[r][e];
    float sg = (dd > 0.f) ? 1.f : ((dd < 0.f) ? -1.f : 0.f);
    out_decay[(row0+r)*DDIM + e] = 0.5f*(1.f - tanhf(sg*fabsf(acc)));
  }
}

// =====================================================================
// Weight conversion: fp32 -> f16 MFMA B-fragment blocks (unchanged)
// =====================================================================
__global__ __launch_bounds__(256) void conv_kernel(
    const float* __restrict__ W_dh, const float* __restrict__ hist_W,
    const float* __restrict__ feat_W, const float* __restrict__ wcomb_W,
    const float* __restrict__ W_ih, const float* __restrict__ W_hh,
    f16* __restrict__ ws)
{
  const int g  = blockIdx.x*4 + (threadIdx.x >> 6);
  const int l  = threadIdx.x & 63;
  const int nl = l & 15;
  const int kh = (l >> 4) * 8;
  f16x8 out;
  if (g < 576){                                   // GRU
    int jb = g/36, s = g - jb*36;
    if (s < 24){                                  // r or z (fused ih+hh)
      int gate = s/12, kt = s - gate*12;
      int row  = gate*256 + jb*16 + nl;
      #pragma unroll
      for (int e = 0; e < 8; e++){
        int k = kt*32 + kh + e;
        float v = (k < 256) ? W_hh[(size_t)row*256 + k]
                : (k < 374) ? W_ih[(size_t)row*118 + (k-256)] : 0.f;
        out[e] = (f16)v;
      }
    } else if (s < 32){                           // n-gate hidden part
      int kt = s - 24, row = 512 + jb*16 + nl;
      #pragma unroll
      for (int e = 0; e < 8; e++){
        int k = kt*32 + kh + e;
        out[e] = (f16)W_hh[(size_t)row*256 + k];
      }
    } else {                                      // n-gate input part
      int kt = s - 32, row = 512 + jb*16 + nl;
      #pragma unroll
      for (int e = 0; e < 8; e++){
        int k = kt*32 + kh + e;
        out[e] = (f16)((k < 118) ? W_ih[(size_t)row*118 + k] : 0.f);
      }
    }
    *(f16x8*)&ws[WOFF_GRU + (size_t)g*512 + l*8] = out;
  } else if (g < 608){                            // gamma_h decay W_dh
    int i = g - 576, nt = i >> 1, kt = i & 1;
    int row = nt*16 + nl;
    #pragma unroll
    for (int e = 0; e < 8; e++){
      int k = kt*32 + kh + e;
      out[e] = (f16)((k < 59) ? W_dh[(size_t)row*59 + k] : 0.f);
    }
    *(f16x8*)&ws[WOFF_DH + (size_t)i*512 + l*8] = out;
  } else if (g < 640){                            // hist_W
    int i = g - 608, nt = i >> 3, kt = i & 7;
    int n = nt*16 + nl;
    #pragma unroll
    for (int e = 0; e < 8; e++){
      int k = kt*32 + kh + e;
      out[e] = (f16)((n < 59) ? hist_W[(size_t)n*256 + k] : 0.f);
    }
    *(f16x8*)&ws[WOFF_HIST + (size_t)i*512 + l*8] = out;
  } else if (g < 648){                            // feat_W (off-diag mask baked in)
    int i = g - 640, nt = i >> 1, kt = i & 1;
    int n = nt*16 + nl;
    #pragma unroll
    for (int e = 0; e < 8; e++){
      int k = kt*32 + kh + e;
      out[e] = (f16)((n < 59 && k < 59 && k != n) ? feat_W[(size_t)n*59 + k] : 0.f);
    }
    *(f16x8*)&ws[WOFF_FEAT + (size_t)i*512 + l*8] = out;
  } else {                                        // wcomb_W
    int i = g - 648, nt = i >> 2, kt = i & 3;
    int n = nt*16 + nl;
    #pragma unroll
    for (int e = 0; e < 8; e++){
      int k = kt*32 + kh + e;
      out[e] = (f16)((n < 59 && k < 118) ? wcomb_W[(size_t)n*118 + k] : 0.f);
    }
    *(f16x8*)&ws[WOFF_WC + (size_t)i*512 + l*8] = out;
  }
}

// =====================================================================
// Sequential scan: 16 waves/WG, RR=16, NWG=256 (1 WG/CU, 16 waves/CU).
// Cache hygiene: out_hs stored non-temporally (full-line coverage, no
// RMW) and x/m/d loaded non-temporally (read-once) so the 664 KB packed
// weight set stays L2-resident against streaming traffic.
// =====================================================================
__global__ __launch_bounds__(NTHR) void seq_kernel(
    const float* __restrict__ x, const float* __restrict__ mask,
    const float* __restrict__ deltas, const float* __restrict__ h0,
    const float* __restrict__ b_dh, const float* __restrict__ W_dx,
    const float* __restrict__ b_dx, const float* __restrict__ hist_b,
    const float* __restrict__ feat_b, const float* __restrict__ wcomb_b,
    const float* __restrict__ b_ih, const float* __restrict__ b_hh,
    const f16* __restrict__ wb,
    float* __restrict__ out_ximp, float* __restrict__ out_hs,
    float* __restrict__ ws_num, float* __restrict__ ws_den)
{
  __shared__ f16 Acat[RR*392];    // [h(0:256) | x_imp(256:315) | m(315:374) | pad]
  __shared__ f16 AdAxr[RR*72];    // deltas (P0-P1) then x_r (P3-P4); pad 59:72
  __shared__ f16 Agm [RR*136];    // [gamma_x(0:59) | m(59:118) | pad]
  __shared__ f16 ssx [RR*60];     // x
  __shared__ f16 sxh [RR*60];     // x_h
  __shared__ f16 sxu [RR*60];     // feat output
  __shared__ f16 sbt [RR*60];     // beta
  __shared__ float sh [RR*260];   // fp32 hidden state
  __shared__ float sdiag[64], sbdx[64];
  __shared__ float sredN[16], sredD[16];

  const int tid = threadIdx.x;
  const int w   = tid >> 6;          // 0..15
  const int l   = tid & 63;
  const int nl  = l & 15;
  const int kh  = (l >> 4) * 8;
  const int mq  = (l >> 4) * 4;
  const int row0 = blockIdx.x * RR;

  const f16* Bgru  = wb + WOFF_GRU;
  const f16* Bdh   = wb + WOFF_DH;
  const f16* Bhist = wb + WOFF_HIST;
  const f16* Bfeat = wb + WOFF_FEAT;
  const f16* Bwc   = wb + WOFF_WC;
  const f16* Bb    = Bgru + (size_t)w*36*512;   // this wave's GRU jb slice

  // staging slot (single: 944 < 1024 threads)
  const bool hasS = (tid < RR*DDIM);
  const int r0s = tid/59, d0s = tid - r0s*59;

  // hoisted per-thread biases
  const int nG = w*16 + nl;                       // gamma_h col & GRU j
  const float bdh_n = b_dh[nG];
  const float br_j  = b_ih[nG]     + b_hh[nG];
  const float bz_j  = b_ih[256+nG] + b_hh[256+nG];
  const float bni_j = b_ih[512+nG];
  const float bnh_j = b_hh[512+nG];
  const int nA = w*16 + nl;                       // waves 0-3: x_h/feat col
  const int nB = (w-4)*16 + nl;                   // waves 4-7: beta col
  const float hb_n = (w < 4 && nA < DDIM) ? hist_b[nA] : 0.f;
  const float fb_n = (w < 4 && nA < DDIM) ? feat_b[nA] : 0.f;
  const float cb_n = (w >= 4 && w < 8 && nB < DDIM) ? wcomb_b[nB] : 0.f;

  if (tid < DDIM){ sdiag[tid] = W_dx[(size_t)tid*DDIM + tid]; sbdx[tid] = b_dx[tid]; }
  // zero pads once
  for (int idx = tid; idx < RR*18; idx += NTHR){
    int r = idx/18, c = idx - (idx/18)*18;
    Acat[r*392 + 374 + c] = (f16)0.f;
    Agm [r*136 + 118 + c] = (f16)0.f;
  }
  for (int idx = tid; idx < RR*13; idx += NTHR){
    int r = idx/13, c = idx - (idx/13)*13;
    AdAxr[r*72 + 59 + c] = (f16)0.f;
  }
  for (int idx = tid; idx < RR*HHID; idx += NTHR){
    int r = idx >> 8, j = idx & 255;
    sh[r*260 + j] = h0[(size_t)(row0+r)*HHID + j];
  }

  // prologue prefetch (t = 0)
  float vx0 = 0.f, vm0 = 0.f, vd0 = 0.f;
  if (hasS){
    size_t g0 = ((size_t)(row0+r0s)*TT)*DDIM + d0s;
    vx0 = __builtin_nontemporal_load(&x[g0]);
    vm0 = __builtin_nontemporal_load(&mask[g0]);
    vd0 = __builtin_nontemporal_load(&deltas[g0]);
  }
  __syncthreads();

  for (int t = 0; t < TT; t++){
    // ---- P0: stage prefetched x, m, d ----
    if (hasS){
      ssx[r0s*60+d0s] = (f16)vx0;
      AdAxr[r0s*72+d0s] = (f16)vd0;
      Agm[r0s*136+59+d0s] = (f16)vm0;
      Acat[r0s*392+315+d0s] = (f16)vm0;
    }
    __syncthreads();

    // issue next step's loads (latency hidden under compute)
    if (t + 1 < TT && hasS){
      size_t g0 = ((size_t)(row0+r0s)*TT + (t+1))*DDIM + d0s;
      vx0 = __builtin_nontemporal_load(&x[g0]);
      vm0 = __builtin_nontemporal_load(&mask[g0]);
      vd0 = __builtin_nontemporal_load(&deltas[g0]);
    }

    // ---- P1: gamma_h MFMA (1 nt per wave) + gamma_x VALU ----
    {
      f32x4 acc = {0.f,0.f,0.f,0.f};
      #pragma unroll
      for (int kt = 0; kt < 2; kt++){
        f16x8 a = *(const f16x8*)&AdAxr[nl*72 + kt*32 + kh];
        f16x8 b = *(const f16x8*)&Bdh[(size_t)(w*2+kt)*512 + l*8];
        acc = __builtin_amdgcn_mfma_f32_16x16x32_f16(a, b, acc, 0, 0, 0);
      }
      #pragma unroll
      for (int q = 0; q < 4; q++){
        float gm = expf(-fmaxf(acc[q] + bdh_n, 0.f));
        float hv = sh[(mq+q)*260 + nG] * gm;
        sh[(mq+q)*260 + nG] = hv;
        Acat[(mq+q)*392 + nG] = (f16)hv;
      }
      if (hasS){
        float dv = (float)AdAxr[r0s*72 + d0s];
        float gx = expf(-fmaxf(dv*sdiag[d0s] + sbdx[d0s], 0.f));
        Agm[r0s*136 + d0s] = (f16)gx;
      }
    }
    __syncthreads();

    // ---- P2: GRU h-part (all 16 waves, kt 0-7) then x_h / beta ----
    f32x4 gr = {0.f,0.f,0.f,0.f}, gz = {0.f,0.f,0.f,0.f}, gnh = {0.f,0.f,0.f,0.f};
    {
      #pragma unroll
      for (int kt = 0; kt < 8; kt++){
        f16x8 a  = *(const f16x8*)&Acat[nl*392 + kt*32 + kh];
        f16x8 br = *(const f16x8*)&Bb[(size_t)kt*512 + l*8];
        f16x8 bz = *(const f16x8*)&Bb[(size_t)(12+kt)*512 + l*8];
        f16x8 bn = *(const f16x8*)&Bb[(size_t)(24+kt)*512 + l*8];
        gr  = __builtin_amdgcn_mfma_f32_16x16x32_f16(a, br, gr, 0, 0, 0);
        gz  = __builtin_amdgcn_mfma_f32_16x16x32_f16(a, bz, gz, 0, 0, 0);
        gnh = __builtin_amdgcn_mfma_f32_16x16x32_f16(a, bn, gnh, 0, 0, 0);
      }
      if (w < 4){                               // x_h
        f32x4 acc = {0.f,0.f,0.f,0.f};
        #pragma unroll
        for (int kt = 0; kt < 8; kt++){
          f16x8 a = *(const f16x8*)&Acat[nl*392 + kt*32 + kh];
          f16x8 b = *(const f16x8*)&Bhist[(size_t)(w*8+kt)*512 + l*8];
          acc = __builtin_amdgcn_mfma_f32_16x16x32_f16(a, b, acc, 0, 0, 0);
        }
        if (nA < DDIM){
          #pragma unroll
          for (int q = 0; q < 4; q++) sxh[(mq+q)*60 + nA] = (f16)(acc[q] + hb_n);
        }
      } else if (w < 8){                        // beta
        f32x4 acc = {0.f,0.f,0.f,0.f};
        #pragma unroll
        for (int kt = 0; kt < 4; kt++){
          f16x8 a = *(const f16x8*)&Agm[nl*136 + kt*32 + kh];
          f16x8 b = *(const f16x8*)&Bwc[(size_t)((w-4)*4+kt)*512 + l*8];
          acc = __builtin_amdgcn_mfma_f32_16x16x32_f16(a, b, acc, 0, 0, 0);
        }
        if (nB < DDIM){
          #pragma unroll
          for (int q = 0; q < 4; q++) sbt[(mq+q)*60 + nB] = (f16)sigm(acc[q] + cb_n);
        }
      }
    }
    __syncthreads();

    // ---- P3: x_r (overwrites AdAxr) ----
    if (hasS){
      float m  = (float)Acat[r0s*392 + 315 + d0s];
      float xr = m*(float)ssx[r0s*60+d0s] + (1.f-m)*(float)sxh[r0s*60+d0s];
      AdAxr[r0s*72+d0s] = (f16)xr;
    }
    __syncthreads();

    // ---- P4: feat MFMA (waves 0-3) ----
    if (w < 4){
      f32x4 acc = {0.f,0.f,0.f,0.f};
      #pragma unroll
      for (int kt = 0; kt < 2; kt++){
        f16x8 a = *(const f16x8*)&AdAxr[nl*72 + kt*32 + kh];
        f16x8 b = *(const f16x8*)&Bfeat[(size_t)(w*2+kt)*512 + l*8];
        acc = __builtin_amdgcn_mfma_f32_16x16x32_f16(a, b, acc, 0, 0, 0);
      }
      if (nA < DDIM){
        #pragma unroll
        for (int q = 0; q < 4; q++) sxu[(mq+q)*60 + nA] = (f16)(acc[q] + fb_n);
      }
    }
    __syncthreads();

    // ---- P5: x_comb / loss / x_imp ----
    float lnum = 0.f, lden = 0.f;
    if (hasS){
      float xh = (float)sxh[r0s*60+d0s], xu = (float)sxu[r0s*60+d0s];
      float bt = (float)sbt[r0s*60+d0s];
      float xc = bt*xu + (1.f-bt)*xh;
      float m  = (float)Acat[r0s*392 + 315 + d0s];
      float xv = (float)ssx[r0s*60+d0s];
      lnum = fabsf(xv - xc)*m;
      lden = m;
      float xi = m*xv + (1.f-m)*xc;
      Acat[r0s*392 + 256 + d0s] = (f16)xi;
      out_ximp[((size_t)(row0+r0s)*TT + t)*DDIM + d0s] = xi;
    }
    #pragma unroll
    for (int off = 32; off >= 1; off >>= 1){
      lnum += __shfl_xor(lnum, off);
      lden += __shfl_xor(lden, off);
    }
    if (l == 0){ sredN[w] = lnum; sredD[w] = lden; }
    __syncthreads();
    if (tid == 0){
      float a = 0.f, b = 0.f;
      #pragma unroll
      for (int k = 0; k < 16; k++){ a += sredN[k]; b += sredD[k]; }
      atomicAdd(&ws_num[t], a); atomicAdd(&ws_den[t], b);
    }

    // ---- P6: GRU finish (kt 8-11 over [x_imp|m]) + gates + h update ----
    {
      f32x4 gni = {0.f,0.f,0.f,0.f};
      #pragma unroll
      for (int kt = 8; kt < 12; kt++){
        f16x8 a  = *(const f16x8*)&Acat[nl*392 + kt*32 + kh];
        f16x8 br = *(const f16x8*)&Bb[(size_t)kt*512 + l*8];
        f16x8 bz = *(const f16x8*)&Bb[(size_t)(12+kt)*512 + l*8];
        f16x8 bn = *(const f16x8*)&Bb[(size_t)(32+kt-8)*512 + l*8];
        gr  = __builtin_amdgcn_mfma_f32_16x16x32_f16(a, br, gr, 0, 0, 0);
        gz  = __builtin_amdgcn_mfma_f32_16x16x32_f16(a, bz, gz, 0, 0, 0);
        gni = __builtin_amdgcn_mfma_f32_16x16x32_f16(a, bn, gni, 0, 0, 0);
      }
      #pragma unroll
      for (int q = 0; q < 4; q++){
        float rg = sigm(gr[q] + br_j);
        float zg = sigm(gz[q] + bz_j);
        float ng = tanhf(gni[q] + bni_j + rg*(gnh[q] + bnh_j));
        float hold = sh[(mq+q)*260 + nG];
        float hn = (1.f-zg)*ng + zg*hold;
        sh[(mq+q)*260 + nG] = hn;
        __builtin_nontemporal_store(hn, &out_hs[((size_t)(row0+mq+q)*TT + t)*HHID + nG]);
      }
    }
    __syncthreads();
  }
}

// =====================================================================
// finalize: x_loss and classification head
// =====================================================================
__global__ __launch_bounds__(256) void final_kernel(
    const float* __restrict__ hs, const float* __restrict__ cls_W,
    const float* __restrict__ cls_b, const float* __restrict__ ws_num,
    const float* __restrict__ ws_den, float* __restrict__ out)
{
  int b = blockIdx.x*256 + threadIdx.x;
  if (b < BATCH){
    const float* hr = hs + ((size_t)b*TT + (TT-1))*HHID;
    float acc = cls_b[0];
    for (int j = 0; j < HHID; j++) acc += hr[j]*cls_W[j];
    out[OFF_YOUT + b] = acc;
    out[OFF_YSC  + b] = sigm(acc);
  }
  if (blockIdx.x == 0 && threadIdx.x == 0){
    float s = 0.f;
    for (int tt = 0; tt < TT; tt++) s += ws_num[tt]/(ws_den[tt] + 1e-5f);
    out[OFF_LOSS] = s;
  }
}

extern "C" void kernel_launch(void* const* d_in, const int* in_sizes, int n_in,
                              void* d_out, int out_size, void* d_ws, size_t ws_size,
                              hipStream_t stream)
{
  const float* x       = (const float*)d_in[0];
  const float* mask_   = (const float*)d_in[1];
  const float* deltas  = (const float*)d_in[2];
  const float* h0      = (const float*)d_in[4];
  const float* medians = (const float*)d_in[5];
  const float* W_dh    = (const float*)d_in[6];
  const float* b_dh    = (const float*)d_in[7];
  const float* W_dx    = (const float*)d_in[8];
  const float* b_dx    = (const float*)d_in[9];
  const float* hist_W  = (const float*)d_in[10];
  const float* hist_b  = (const float*)d_in[11];
  const float* feat_W  = (const float*)d_in[12];
  const float* feat_b  = (const float*)d_in[13];
  const float* wcomb_W = (const float*)d_in[14];
  const float* wcomb_b = (const float*)d_in[15];
  const float* wobs_W  = (const float*)d_in[16];
  const float* wobs_b  = (const float*)d_in[17];
  const float* W_ih    = (const float*)d_in[18];
  const float* W_hh    = (const float*)d_in[19];
  const float* b_ih    = (const float*)d_in[20];
  const float* b_hh    = (const float*)d_in[21];
  const float* cls_W   = (const float*)d_in[22];
  const float* cls_b   = (const float*)d_in[23];

  float* out    = (float*)d_out;
  float* ws_num = (float*)d_ws;              // 48 floats
  float* ws_den = ws_num + TT;               // 48 floats
  f16*   wbase  = (f16*)((char*)d_ws + 512); // f16 weight blocks

  hipMemsetAsync(d_ws, 0, 512, stream);

  conv_kernel<<<166, 256, 0, stream>>>(W_dh, hist_W, feat_W, wcomb_W,
                                       W_ih, W_hh, wbase);

  decay_kernel<<<BATCH*TT/16, 256, 0, stream>>>(deltas, medians, wobs_W, wobs_b,
                                                out + OFF_DEC);

  seq_kernel<<<NWG, NTHR, 0, stream>>>(x, mask_, deltas, h0,
      b_dh, W_dx, b_dx, hist_b, feat_b, wcomb_b, b_ih, b_hh, wbase,
      out /*x_imp*/, out + OFF_HS, ws_num, ws_den);

  final_kernel<<<BATCH/256, 256, 0, stream>>>(out + OFF_HS, cls_W, cls_b,
                                              ws_num, ws_den, out);
}

// Round 8
// 1481.923 us; speedup vs baseline: 1.7576x; 1.0285x over previous
//
#include <hip/hip_runtime.h>
#include <math.h>

#define BATCH 4096
#define TT 48
#define DDIM 59
#define HHID 256
#define RR 16              // batch rows per workgroup
#define NWG (BATCH/RR)     // 256 workgroups (1 per CU)
#define NTHR 1024          // 16 waves

typedef _Float16 f16;
typedef _Float16 f16x8 __attribute__((ext_vector_type(8)));
typedef float    f32x4 __attribute__((ext_vector_type(4)));

// ---- output layout (floats) ----
static constexpr size_t N_XIMP   = (size_t)BATCH*TT*DDIM;
static constexpr size_t OFF_LOSS = N_XIMP;
static constexpr size_t OFF_HS   = OFF_LOSS + 1;
static constexpr size_t N_HS     = (size_t)BATCH*TT*HHID;
static constexpr size_t OFF_YOUT = OFF_HS + N_HS;
static constexpr size_t OFF_YSC  = OFF_YOUT + BATCH;
static constexpr size_t OFF_DEC  = OFF_YSC + BATCH;

// ---- f16 weight workspace layout (element offsets from wbase) ----
static constexpr size_t WOFF_GRU  = 0;          // 16 jb * 36 blocks
static constexpr size_t WOFF_DH   = 294912;     // 16 nt * 2 kt
static constexpr size_t WOFF_HIST = 311296;     // 4 nt * 8 kt
static constexpr size_t WOFF_FEAT = 327680;     // 4 nt * 2 kt
static constexpr size_t WOFF_WC   = 331776;     // 4 nt * 4 kt

__device__ __forceinline__ float sigm(float v){ return 1.f/(1.f+expf(-v)); }

// =====================================================================
// decay_factor (fully parallel)
// =====================================================================
__global__ __launch_bounds__(256) void decay_kernel(
    const float* __restrict__ deltas, const float* __restrict__ medians,
    const float* __restrict__ wobs_W, const float* __restrict__ wobs_b,
    float* __restrict__ out_decay)
{
  __shared__ float sW[DDIM][60];
  __shared__ float sb[64], smed[64];
  __shared__ float sdd[16][60];
  const int tid = threadIdx.x;
  for (int idx = tid; idx < DDIM*DDIM; idx += 256){
    int e = idx/DDIM, d = idx - e*DDIM;
    sW[e][d] = wobs_W[idx];
  }
  if (tid < DDIM){ sb[tid] = wobs_b[tid]; smed[tid] = medians[tid]; }
  __syncthreads();
  const size_t row0 = (size_t)blockIdx.x * 16;
  for (int idx = tid; idx < 16*DDIM; idx += 256){
    int r = idx/DDIM, d = idx - r*DDIM;
    sdd[r][d] = __builtin_nontemporal_load(&deltas[(row0+r)*DDIM + d]) - smed[d];
  }
  __syncthreads();
  for (int idx = tid; idx < 16*DDIM; idx += 256){
    int r = idx/DDIM, e = idx - r*DDIM;
    float acc = sb[e];
    for (int d = 0; d < DDIM; d++) acc += sdd[r][d]*sW[e][d];
    float dd = sdd[r][e];
    float sg = (dd > 0.f) ? 1.f : ((dd < 0.f) ? -1.f : 0.f);
    out_decay[(row0+r)*DDIM + e] = 0.5f*(1.f - tanhf(sg*fabsf(acc)));
  }
}

// =====================================================================
// Weight conversion: fp32 -> f16 MFMA B-fragment blocks (unchanged)
// =====================================================================
__global__ __launch_bounds__(256) void conv_kernel(
    const float* __restrict__ W_dh, const float* __restrict__ hist_W,
    const float* __restrict__ feat_W, const float* __restrict__ wcomb_W,
    const float* __restrict__ W_ih, const float* __restrict__ W_hh,
    f16* __restrict__ ws)
{
  const int g  = blockIdx.x*4 + (threadIdx.x >> 6);
  const int l  = threadIdx.x & 63;
  const int nl = l & 15;
  const int kh = (l >> 4) * 8;
  f16x8 out;
  if (g < 576){                                   // GRU
    int jb = g/36, s = g - jb*36;
    if (s < 24){                                  // r or z (fused ih+hh)
      int gate = s/12, kt = s - gate*12;
      int row  = gate*256 + jb*16 + nl;
      #pragma unroll
      for (int e = 0; e < 8; e++){
        int k = kt*32 + kh + e;
        float v = (k < 256) ? W_hh[(size_t)row*256 + k]
                : (k < 374) ? W_ih[(size_t)row*118 + (k-256)] : 0.f;
        out[e] = (f16)v;
      }
    } else if (s < 32){                           // n-gate hidden part
      int kt = s - 24, row = 512 + jb*16 + nl;
      #pragma unroll
      for (int e = 0; e < 8; e++){
        int k = kt*32 + kh + e;
        out[e] = (f16)W_hh[(size_t)row*256 + k];
      }
    } else {                                      // n-gate input part
      int kt = s - 32, row = 512 + jb*16 + nl;
      #pragma unroll
      for (int e = 0; e < 8; e++){
        int k = kt*32 + kh + e;
        out[e] = (f16)((k < 118) ? W_ih[(size_t)row*118 + k] : 0.f);
      }
    }
    *(f16x8*)&ws[WOFF_GRU + (size_t)g*512 + l*8] = out;
  } else if (g < 608){                            // gamma_h decay W_dh
    int i = g - 576, nt = i >> 1, kt = i & 1;
    int row = nt*16 + nl;
    #pragma unroll
    for (int e = 0; e < 8; e++){
      int k = kt*32 + kh + e;
      out[e] = (f16)((k < 59) ? W_dh[(size_t)row*59 + k] : 0.f);
    }
    *(f16x8*)&ws[WOFF_DH + (size_t)i*512 + l*8] = out;
  } else if (g < 640){                            // hist_W
    int i = g - 608, nt = i >> 3, kt = i & 7;
    int n = nt*16 + nl;
    #pragma unroll
    for (int e = 0; e < 8; e++){
      int k = kt*32 + kh + e;
      out[e] = (f16)((n < 59) ? hist_W[(size_t)n*256 + k] : 0.f);
    }
    *(f16x8*)&ws[WOFF_HIST + (size_t)i*512 + l*8] = out;
  } else if (g < 648){                            // feat_W (off-diag mask baked in)
    int i = g - 640, nt = i >> 1, kt = i & 1;
    int n = nt*16 + nl;
    #pragma unroll
    for (int e = 0; e < 8; e++){
      int k = kt*32 + kh + e;
      out[e] = (f16)((n < 59 && k < 59 && k != n) ? feat_W[(size_t)n*59 + k] : 0.f);
    }
    *(f16x8*)&ws[WOFF_FEAT + (size_t)i*512 + l*8] = out;
  } else {                                        // wcomb_W
    int i = g - 648, nt = i >> 2, kt = i & 3;
    int n = nt*16 + nl;
    #pragma unroll
    for (int e = 0; e < 8; e++){
      int k = kt*32 + kh + e;
      out[e] = (f16)((n < 59 && k < 118) ? wcomb_W[(size_t)n*118 + k] : 0.f);
    }
    *(f16x8*)&ws[WOFF_WC + (size_t)i*512 + l*8] = out;
  }
}

// =====================================================================
// Sequential scan: 16 waves/WG, RR=16, NWG=256.
// P7: out_hs written via LDS-staged full-line f32x4 nt stores (wave w
// streams row w of sh: 64 lanes x 16 B = 1024 contiguous aligned bytes)
// -> no write-allocate, no partial-line RMW.
// =====================================================================
__global__ __launch_bounds__(NTHR) void seq_kernel(
    const float* __restrict__ x, const float* __restrict__ mask,
    const float* __restrict__ deltas, const float* __restrict__ h0,
    const float* __restrict__ b_dh, const float* __restrict__ W_dx,
    const float* __restrict__ b_dx, const float* __restrict__ hist_b,
    const float* __restrict__ feat_b, const float* __restrict__ wcomb_b,
    const float* __restrict__ b_ih, const float* __restrict__ b_hh,
    const f16* __restrict__ wb,
    float* __restrict__ out_ximp, float* __restrict__ out_hs,
    float* __restrict__ ws_num, float* __restrict__ ws_den)
{
  __shared__ f16 Acat[RR*392];    // [h(0:256) | x_imp(256:315) | m(315:374) | pad]
  __shared__ f16 AdAxr[RR*72];    // deltas (P0-P1) then x_r (P3-P4); pad 59:72
  __shared__ f16 Agm [RR*136];    // [gamma_x(0:59) | m(59:118) | pad]
  __shared__ f16 ssx [RR*60];     // x
  __shared__ f16 sxh [RR*60];     // x_h
  __shared__ f16 sxu [RR*60];     // feat output
  __shared__ f16 sbt [RR*60];     // beta
  __shared__ float sh [RR*260];   // fp32 hidden state
  __shared__ float sdiag[64], sbdx[64];
  __shared__ float sredN[16], sredD[16];

  const int tid = threadIdx.x;
  const int w   = tid >> 6;          // 0..15
  const int l   = tid & 63;
  const int nl  = l & 15;
  const int kh  = (l >> 4) * 8;
  const int mq  = (l >> 4) * 4;
  const int row0 = blockIdx.x * RR;

  const f16* Bgru  = wb + WOFF_GRU;
  const f16* Bdh   = wb + WOFF_DH;
  const f16* Bhist = wb + WOFF_HIST;
  const f16* Bfeat = wb + WOFF_FEAT;
  const f16* Bwc   = wb + WOFF_WC;
  const f16* Bb    = Bgru + (size_t)w*36*512;   // this wave's GRU jb slice

  // staging slot (single: 944 < 1024 threads)
  const bool hasS = (tid < RR*DDIM);
  const int r0s = tid/59, d0s = tid - r0s*59;

  // hoisted per-thread biases
  const int nG = w*16 + nl;                       // gamma_h col & GRU j
  const float bdh_n = b_dh[nG];
  const float br_j  = b_ih[nG]     + b_hh[nG];
  const float bz_j  = b_ih[256+nG] + b_hh[256+nG];
  const float bni_j = b_ih[512+nG];
  const float bnh_j = b_hh[512+nG];
  const int nA = w*16 + nl;                       // waves 0-3: x_h/feat col
  const int nB = (w-4)*16 + nl;                   // waves 4-7: beta col
  const float hb_n = (w < 4 && nA < DDIM) ? hist_b[nA] : 0.f;
  const float fb_n = (w < 4 && nA < DDIM) ? feat_b[nA] : 0.f;
  const float cb_n = (w >= 4 && w < 8 && nB < DDIM) ? wcomb_b[nB] : 0.f;

  if (tid < DDIM){ sdiag[tid] = W_dx[(size_t)tid*DDIM + tid]; sbdx[tid] = b_dx[tid]; }
  // zero pads once
  for (int idx = tid; idx < RR*18; idx += NTHR){
    int r = idx/18, c = idx - (idx/18)*18;
    Acat[r*392 + 374 + c] = (f16)0.f;
    Agm [r*136 + 118 + c] = (f16)0.f;
  }
  for (int idx = tid; idx < RR*13; idx += NTHR){
    int r = idx/13, c = idx - (idx/13)*13;
    AdAxr[r*72 + 59 + c] = (f16)0.f;
  }
  for (int idx = tid; idx < RR*HHID; idx += NTHR){
    int r = idx >> 8, j = idx & 255;
    sh[r*260 + j] = h0[(size_t)(row0+r)*HHID + j];
  }

  // prologue prefetch (t = 0)
  float vx0 = 0.f, vm0 = 0.f, vd0 = 0.f;
  if (hasS){
    size_t g0 = ((size_t)(row0+r0s)*TT)*DDIM + d0s;
    vx0 = __builtin_nontemporal_load(&x[g0]);
    vm0 = __builtin_nontemporal_load(&mask[g0]);
    vd0 = __builtin_nontemporal_load(&deltas[g0]);
  }
  __syncthreads();

  for (int t = 0; t < TT; t++){
    // ---- P0: stage prefetched x, m, d ----
    if (hasS){
      ssx[r0s*60+d0s] = (f16)vx0;
      AdAxr[r0s*72+d0s] = (f16)vd0;
      Agm[r0s*136+59+d0s] = (f16)vm0;
      Acat[r0s*392+315+d0s] = (f16)vm0;
    }
    __syncthreads();

    // issue next step's loads (latency hidden under compute)
    if (t + 1 < TT && hasS){
      size_t g0 = ((size_t)(row0+r0s)*TT + (t+1))*DDIM + d0s;
      vx0 = __builtin_nontemporal_load(&x[g0]);
      vm0 = __builtin_nontemporal_load(&mask[g0]);
      vd0 = __builtin_nontemporal_load(&deltas[g0]);
    }

    // ---- P1: gamma_h MFMA (1 nt per wave) + gamma_x VALU ----
    {
      f32x4 acc = {0.f,0.f,0.f,0.f};
      #pragma unroll
      for (int kt = 0; kt < 2; kt++){
        f16x8 a = *(const f16x8*)&AdAxr[nl*72 + kt*32 + kh];
        f16x8 b = *(const f16x8*)&Bdh[(size_t)(w*2+kt)*512 + l*8];
        acc = __builtin_amdgcn_mfma_f32_16x16x32_f16(a, b, acc, 0, 0, 0);
      }
      #pragma unroll
      for (int q = 0; q < 4; q++){
        float gm = expf(-fmaxf(acc[q] + bdh_n, 0.f));
        float hv = sh[(mq+q)*260 + nG] * gm;
        sh[(mq+q)*260 + nG] = hv;
        Acat[(mq+q)*392 + nG] = (f16)hv;
      }
      if (hasS){
        float dv = (float)AdAxr[r0s*72 + d0s];
        float gx = expf(-fmaxf(dv*sdiag[d0s] + sbdx[d0s], 0.f));
        Agm[r0s*136 + d0s] = (f16)gx;
      }
    }
    __syncthreads();

    // ---- P2: GRU h-part (all 16 waves, kt 0-7) then x_h / beta ----
    f32x4 gr = {0.f,0.f,0.f,0.f}, gz = {0.f,0.f,0.f,0.f}, gnh = {0.f,0.f,0.f,0.f};
    {
      #pragma unroll
      for (int kt = 0; kt < 8; kt++){
        f16x8 a  = *(const f16x8*)&Acat[nl*392 + kt*32 + kh];
        f16x8 br = *(const f16x8*)&Bb[(size_t)kt*512 + l*8];
        f16x8 bz = *(const f16x8*)&Bb[(size_t)(12+kt)*512 + l*8];
        f16x8 bn = *(const f16x8*)&Bb[(size_t)(24+kt)*512 + l*8];
        gr  = __builtin_amdgcn_mfma_f32_16x16x32_f16(a, br, gr, 0, 0, 0);
        gz  = __builtin_amdgcn_mfma_f32_16x16x32_f16(a, bz, gz, 0, 0, 0);
        gnh = __builtin_amdgcn_mfma_f32_16x16x32_f16(a, bn, gnh, 0, 0, 0);
      }
      if (w < 4){                               // x_h
        f32x4 acc = {0.f,0.f,0.f,0.f};
        #pragma unroll
        for (int kt = 0; kt < 8; kt++){
          f16x8 a = *(const f16x8*)&Acat[nl*392 + kt*32 + kh];
          f16x8 b = *(const f16x8*)&Bhist[(size_t)(w*8+kt)*512 + l*8];
          acc = __builtin_amdgcn_mfma_f32_16x16x32_f16(a, b, acc, 0, 0, 0);
        }
        if (nA < DDIM){
          #pragma unroll
          for (int q = 0; q < 4; q++) sxh[(mq+q)*60 + nA] = (f16)(acc[q] + hb_n);
        }
      } else if (w < 8){                        // beta
        f32x4 acc = {0.f,0.f,0.f,0.f};
        #pragma unroll
        for (int kt = 0; kt < 4; kt++){
          f16x8 a = *(const f16x8*)&Agm[nl*136 + kt*32 + kh];
          f16x8 b = *(const f16x8*)&Bwc[(size_t)((w-4)*4+kt)*512 + l*8];
          acc = __builtin_amdgcn_mfma_f32_16x16x32_f16(a, b, acc, 0, 0, 0);
        }
        if (nB < DDIM){
          #pragma unroll
          for (int q = 0; q < 4; q++) sbt[(mq+q)*60 + nB] = (f16)sigm(acc[q] + cb_n);
        }
      }
    }
    __syncthreads();

    // ---- P3: x_r (overwrites AdAxr) ----
    if (hasS){
      float m  = (float)Acat[r0s*392 + 315 + d0s];
      float xr = m*(float)ssx[r0s*60+d0s] + (1.f-m)*(float)sxh[r0s*60+d0s];
      AdAxr[r0s*72+d0s] = (f16)xr;
    }
    __syncthreads();

    // ---- P4: feat MFMA (waves 0-3) ----
    if (w < 4){
      f32x4 acc = {0.f,0.f,0.f,0.f};
      #pragma unroll
      for (int kt = 0; kt < 2; kt++){
        f16x8 a = *(const f16x8*)&AdAxr[nl*72 + kt*32 + kh];
        f16x8 b = *(const f16x8*)&Bfeat[(size_t)(w*2+kt)*512 + l*8];
        acc = __builtin_amdgcn_mfma_f32_16x16x32_f16(a, b, acc, 0, 0, 0);
      }
      if (nA < DDIM){
        #pragma unroll
        for (int q = 0; q < 4; q++) sxu[(mq+q)*60 + nA] = (f16)(acc[q] + fb_n);
      }
    }
    __syncthreads();

    // ---- P5: x_comb / loss / x_imp ----
    float lnum = 0.f, lden = 0.f;
    if (hasS){
      float xh = (float)sxh[r0s*60+d0s], xu = (float)sxu[r0s*60+d0s];
      float bt = (float)sbt[r0s*60+d0s];
      float xc = bt*xu + (1.f-bt)*xh;
      float m  = (float)Acat[r0s*392 + 315 + d0s];
      float xv = (float)ssx[r0s*60+d0s];
      lnum = fabsf(xv - xc)*m;
      lden = m;
      float xi = m*xv + (1.f-m)*xc;
      Acat[r0s*392 + 256 + d0s] = (f16)xi;
      out_ximp[((size_t)(row0+r0s)*TT + t)*DDIM + d0s] = xi;
    }
    #pragma unroll
    for (int off = 32; off >= 1; off >>= 1){
      lnum += __shfl_xor(lnum, off);
      lden += __shfl_xor(lden, off);
    }
    if (l == 0){ sredN[w] = lnum; sredD[w] = lden; }
    __syncthreads();
    if (tid == 0){
      float a = 0.f, b = 0.f;
      #pragma unroll
      for (int k = 0; k < 16; k++){ a += sredN[k]; b += sredD[k]; }
      atomicAdd(&ws_num[t], a); atomicAdd(&ws_den[t], b);
    }

    // ---- P6: GRU finish (kt 8-11 over [x_imp|m]) + gates + h update ----
    {
      f32x4 gni = {0.f,0.f,0.f,0.f};
      #pragma unroll
      for (int kt = 8; kt < 12; kt++){
        f16x8 a  = *(const f16x8*)&Acat[nl*392 + kt*32 + kh];
        f16x8 br = *(const f16x8*)&Bb[(size_t)kt*512 + l*8];
        f16x8 bz = *(const f16x8*)&Bb[(size_t)(12+kt)*512 + l*8];
        f16x8 bn = *(const f16x8*)&Bb[(size_t)(32+kt-8)*512 + l*8];
        gr  = __builtin_amdgcn_mfma_f32_16x16x32_f16(a, br, gr, 0, 0, 0);
        gz  = __builtin_amdgcn_mfma_f32_16x16x32_f16(a, bz, gz, 0, 0, 0);
        gni = __builtin_amdgcn_mfma_f32_16x16x32_f16(a, bn, gni, 0, 0, 0);
      }
      #pragma unroll
      for (int q = 0; q < 4; q++){
        float rg = sigm(gr[q] + br_j);
        float zg = sigm(gz[q] + bz_j);
        float ng = tanhf(gni[q] + bni_j + rg*(gnh[q] + bnh_j));
        float hold = sh[(mq+q)*260 + nG];
        float hn = (1.f-zg)*ng + zg*hold;
        sh[(mq+q)*260 + nG] = hn;
      }
    }
    __syncthreads();

    // ---- P7: coalesced out_hs write — wave w streams row w of sh ----
    {
      const int j0 = l*4;
      f32x4 v;
      v[0] = sh[w*260 + j0 + 0];
      v[1] = sh[w*260 + j0 + 1];
      v[2] = sh[w*260 + j0 + 2];
      v[3] = sh[w*260 + j0 + 3];
      f32x4* dst = (f32x4*)&out_hs[((size_t)(row0+w)*TT + t)*HHID + j0];
      __builtin_nontemporal_store(v, dst);
    }
    __syncthreads();
  }
}

// =====================================================================
// finalize: x_loss and classification head
// =====================================================================
__global__ __launch_bounds__(256) void final_kernel(
    const float* __restrict__ hs, const float* __restrict__ cls_W,
    const float* __restrict__ cls_b, const float* __restrict__ ws_num,
    const float* __restrict__ ws_den, float* __restrict__ out)
{
  int b = blockIdx.x*256 + threadIdx.x;
  if (b < BATCH){
    const float* hr = hs + ((size_t)b*TT + (TT-1))*HHID;
    float acc = cls_b[0];
    for (int j = 0; j < HHID; j++) acc += hr[j]*cls_W[j];
    out[OFF_YOUT + b] = acc;
    out[OFF_YSC  + b] = sigm(acc);
  }
  if (blockIdx.x == 0 && threadIdx.x == 0){
    float s = 0.f;
    for (int tt = 0; tt < TT; tt++) s += ws_num[tt]/(ws_den[tt] + 1e-5f);
    out[OFF_LOSS] = s;
  }
}

extern "C" void kernel_launch(void* const* d_in, const int* in_sizes, int n_in,
                              void* d_out, int out_size, void* d_ws, size_t ws_size,
                              hipStream_t stream)
{
  const float* x       = (const float*)d_in[0];
  const float* mask_   = (const float*)d_in[1];
  const float* deltas  = (const float*)d_in[2];
  const float* h0      = (const float*)d_in[4];
  const float* medians = (const float*)d_in[5];
  const float* W_dh    = (const float*)d_in[6];
  const float* b_dh    = (const float*)d_in[7];
  const float* W_dx    = (const float*)d_in[8];
  const float* b_dx    = (const float*)d_in[9];
  const float* hist_W  = (const float*)d_in[10];
  const float* hist_b  = (const float*)d_in[11];
  const float* feat_W  = (const float*)d_in[12];
  const float* feat_b  = (const float*)d_in[13];
  const float* wcomb_W = (const float*)d_in[14];
  const float* wcomb_b = (const float*)d_in[15];
  const float* wobs_W  = (const float*)d_in[16];
  const float* wobs_b  = (const float*)d_in[17];
  const float* W_ih    = (const float*)d_in[18];
  const float* W_hh    = (const float*)d_in[19];
  const float* b_ih    = (const float*)d_in[20];
  const float* b_hh    = (const float*)d_in[21];
  const float* cls_W   = (const float*)d_in[22];
  const float* cls_b   = (const float*)d_in[23];

  float* out    = (float*)d_out;
  float* ws_num = (float*)d_ws;              // 48 floats
  float* ws_den = ws_num + TT;               // 48 floats
  f16*   wbase  = (f16*)((char*)d_ws + 512); // f16 weight blocks

  (void)hipMemsetAsync(d_ws, 0, 512, stream);

  conv_kernel<<<166, 256, 0, stream>>>(W_dh, hist_W, feat_W, wcomb_W,
                                       W_ih, W_hh, wbase);

  decay_kernel<<<BATCH*TT/16, 256, 0, stream>>>(deltas, medians, wobs_W, wobs_b,
                                                out + OFF_DEC);

  seq_kernel<<<NWG, NTHR, 0, stream>>>(x, mask_, deltas, h0,
      b_dh, W_dx, b_dx, hist_b, feat_b, wcomb_b, b_ih, b_hh, wbase,
      out /*x_imp*/, out + OFF_HS, ws_num, ws_den);

  final_kernel<<<BATCH/256, 256, 0, stream>>>(out + OFF_HS, cls_W, cls_b,
                                              ws_num, ws_den, out);
}